// Round 1
// baseline (798.598 us; speedup 1.0000x reference)
//
#include <hip/hip_runtime.h>
#include <hip/hip_bf16.h>
#include <stdint.h>

#define H_  16
#define S_  2048
#define D_  2048
#define HD_ 128

typedef __bf16 bf16x8 __attribute__((ext_vector_type(8)));
typedef short  s16x8  __attribute__((ext_vector_type(8)));
typedef float  f32x4  __attribute__((ext_vector_type(4)));
typedef unsigned short u16x4 __attribute__((ext_vector_type(4)));

__device__ __forceinline__ unsigned short f2bf(float f) {
    unsigned u = __builtin_bit_cast(unsigned, f);
    u += 0x7fffu + ((u >> 16) & 1u);
    return (unsigned short)(u >> 16);
}

__device__ __forceinline__ bf16x8 ld_bf8(const unsigned short* p) {
    s16x8 r = *reinterpret_cast<const s16x8*>(p);
    return __builtin_bit_cast(bf16x8, r);
}

#define GLOAD_LDS16(gp, lp)                                                     \
    __builtin_amdgcn_global_load_lds(                                            \
        (const __attribute__((address_space(1))) void*)(gp),                     \
        (__attribute__((address_space(3))) void*)(lp), 16, 0, 0)

// ---------------- cast fp32 -> bf16 ----------------
__global__ __launch_bounds__(256) void cast_f32_bf16(const float* __restrict__ in,
                                                     unsigned short* __restrict__ out,
                                                     int n) {
    int i = (blockIdx.x * 256 + threadIdx.x) * 4;
    if (i >= n) return;
    float4 v = *reinterpret_cast<const float4*>(in + i);
    u16x4 o;
    o[0] = f2bf(v.x); o[1] = f2bf(v.y); o[2] = f2bf(v.z); o[3] = f2bf(v.w);
    *reinterpret_cast<u16x4*>(out + i) = o;
}

// ---------------- QKV GEMM: qkv = x @ W^T + b, scatter to Q/K/V [B,H,S,hd] ----------------
__global__ __launch_bounds__(256) void gemm_bt_qkv(const unsigned short* __restrict__ A,
                                                   const unsigned short* __restrict__ W,
                                                   const float* __restrict__ bias,
                                                   unsigned short* __restrict__ Qo,
                                                   unsigned short* __restrict__ Ko,
                                                   unsigned short* __restrict__ Vo) {
    __shared__ alignas(16) unsigned short As[128 * 32];
    __shared__ alignas(16) unsigned short Bs[128 * 32];
    const int t  = threadIdx.x;
    const int l  = t & 63, w = t >> 6;
    const int wr = w >> 1, wc = w & 1;
    const int lr = l & 15, g = l >> 4;
    const int m0 = blockIdx.y * 128, n0 = blockIdx.x * 128;
    const int Kd = D_;

    f32x4 zero = {0.f, 0.f, 0.f, 0.f};
    f32x4 acc[4][4];
    for (int i = 0; i < 4; ++i)
        for (int j = 0; j < 4; ++j) acc[i][j] = zero;

    const int ea = t * 8;
    const int rowA = ea >> 5, colA = ea & 31;

    for (int kt = 0; kt < Kd; kt += 32) {
        GLOAD_LDS16(A + (size_t)(m0 + rowA) * Kd + kt + colA, &As[ea]);
        GLOAD_LDS16(A + (size_t)(m0 + 64 + rowA) * Kd + kt + colA, &As[2048 + ea]);
        GLOAD_LDS16(W + (size_t)(n0 + rowA) * Kd + kt + colA, &Bs[ea]);
        GLOAD_LDS16(W + (size_t)(n0 + 64 + rowA) * Kd + kt + colA, &Bs[2048 + ea]);
        __syncthreads();
        bf16x8 af[4], bfr[4];
        for (int mi = 0; mi < 4; ++mi) af[mi]  = ld_bf8(&As[(wr * 64 + mi * 16 + lr) * 32 + g * 8]);
        for (int ni = 0; ni < 4; ++ni) bfr[ni] = ld_bf8(&Bs[(wc * 64 + ni * 16 + lr) * 32 + g * 8]);
        for (int mi = 0; mi < 4; ++mi)
            for (int ni = 0; ni < 4; ++ni)
                acc[mi][ni] = __builtin_amdgcn_mfma_f32_16x16x32_bf16(af[mi], bfr[ni], acc[mi][ni], 0, 0, 0);
        __syncthreads();
    }

    for (int mi = 0; mi < 4; ++mi) {
        for (int ni = 0; ni < 4; ++ni) {
            for (int i = 0; i < 4; ++i) {
                int m = m0 + wr * 64 + mi * 16 + g * 4 + i;
                int n = n0 + wc * 64 + ni * 16 + lr;
                float v = acc[mi][ni][i] + bias[n];
                int which = n >> 11;
                int n2 = n & 2047;
                int h = n2 >> 7, d = n2 & 127;
                int b = m >> 11, s = m & 2047;
                size_t idx = (((size_t)(b * H_ + h)) * S_ + s) * HD_ + d;
                unsigned short bv = f2bf(v);
                if (which == 0)      Qo[idx] = bv;
                else if (which == 1) Ko[idx] = bv;
                else                 Vo[idx] = bv;
            }
        }
    }
}

// ---------------- transpose V [B,H,S,hd] -> Vt [B,H,hd,S] ----------------
__global__ void transpose_v(const unsigned short* __restrict__ V,
                            unsigned short* __restrict__ Vt) {
    __shared__ alignas(16) unsigned short tile[32][33];
    const int bh = blockIdx.z;
    const int d0 = blockIdx.x * 32, s0 = blockIdx.y * 32;
    const int tx = threadIdx.x, ty = threadIdx.y;
    for (int r = 0; r < 4; ++r) {
        int s = s0 + ty + r * 8;
        tile[ty + r * 8][tx] = V[((size_t)bh * S_ + s) * HD_ + d0 + tx];
    }
    __syncthreads();
    for (int r = 0; r < 4; ++r) {
        int d = d0 + ty + r * 8;
        Vt[((size_t)bh * HD_ + d) * S_ + s0 + tx] = tile[tx][ty + r * 8];
    }
}

// ---------------- fused attention: 1 wave per 16-query tile ----------------
__global__ __launch_bounds__(64) void attn_kernel(const unsigned short* __restrict__ Q,
                                                  const unsigned short* __restrict__ K,
                                                  const unsigned short* __restrict__ Vt,
                                                  const float* __restrict__ bias,
                                                  unsigned short* __restrict__ O) {
    __shared__ alignas(16) unsigned short Pbuf[16 * 32];
    const int l  = threadIdx.x;
    const int lr = l & 15, g = l >> 4;
    const int q0 = blockIdx.x * 16;
    const int bh = blockIdx.y;
    const int h  = bh & (H_ - 1), b = bh >> 4;
    const unsigned short* Qb = Q + (size_t)bh * S_ * HD_;
    const unsigned short* Kb = K + (size_t)bh * S_ * HD_;
    const unsigned short* Vb = Vt + (size_t)bh * HD_ * S_;
    const float* Bb = bias + (size_t)h * S_ * S_;
    const float scale = 0.08838834764831845f;  // 1/sqrt(128)

    bf16x8 qf[4];
    for (int dc = 0; dc < 4; ++dc)
        qf[dc] = ld_bf8(Qb + (size_t)(q0 + lr) * HD_ + dc * 32 + g * 8);

    f32x4 zero = {0.f, 0.f, 0.f, 0.f};
    f32x4 o[8];
    for (int nc = 0; nc < 8; ++nc) o[nc] = zero;
    float mrow[4], lsum[4];
    for (int i = 0; i < 4; ++i) { mrow[i] = -3.0e38f; lsum[i] = 0.f; }

    const int nchunks = (q0 + 47) >> 5;
    for (int c = 0; c < nchunks; ++c) {
        const int k0 = c * 32;
        f32x4 s0 = zero, s1 = zero;
        for (int dc = 0; dc < 4; ++dc) {
            bf16x8 k0f = ld_bf8(Kb + (size_t)(k0 + lr) * HD_ + dc * 32 + g * 8);
            bf16x8 k1f = ld_bf8(Kb + (size_t)(k0 + 16 + lr) * HD_ + dc * 32 + g * 8);
            s0 = __builtin_amdgcn_mfma_f32_16x16x32_bf16(qf[dc], k0f, s0, 0, 0, 0);
            s1 = __builtin_amdgcn_mfma_f32_16x16x32_bf16(qf[dc], k1f, s1, 0, 0, 0);
        }
        __syncthreads();  // protect Pbuf WAR vs previous iteration's reads
        float corr[4];
        for (int i = 0; i < 4; ++i) {
            int row = q0 + g * 4 + i;
            int c0 = k0 + lr, c1 = k0 + 16 + lr;
            float v0 = (c0 <= row) ? s0[i] * scale + Bb[(size_t)row * S_ + c0] : -3.0e38f;
            float v1 = (c1 <= row) ? s1[i] * scale + Bb[(size_t)row * S_ + c1] : -3.0e38f;
            float mx = fmaxf(v0, v1);
            mx = fmaxf(mx, __shfl_xor(mx, 1));
            mx = fmaxf(mx, __shfl_xor(mx, 2));
            mx = fmaxf(mx, __shfl_xor(mx, 4));
            mx = fmaxf(mx, __shfl_xor(mx, 8));
            float mnew = fmaxf(mrow[i], mx);
            float cf = __expf(mrow[i] - mnew);
            mrow[i] = mnew;
            float e0 = __expf(v0 - mnew);
            float e1 = __expf(v1 - mnew);
            float rs = e0 + e1;
            rs += __shfl_xor(rs, 1);
            rs += __shfl_xor(rs, 2);
            rs += __shfl_xor(rs, 4);
            rs += __shfl_xor(rs, 8);
            lsum[i] = lsum[i] * cf + rs;
            corr[i] = cf;
            Pbuf[(g * 4 + i) * 32 + lr]      = f2bf(e0);
            Pbuf[(g * 4 + i) * 32 + 16 + lr] = f2bf(e1);
        }
        for (int nc = 0; nc < 8; ++nc)
            for (int i = 0; i < 4; ++i) o[nc][i] *= corr[i];
        __syncthreads();
        bf16x8 pa = ld_bf8(&Pbuf[lr * 32 + g * 8]);
        for (int nc = 0; nc < 8; ++nc) {
            bf16x8 vf = ld_bf8(Vb + (size_t)(nc * 16 + lr) * S_ + k0 + g * 8);
            o[nc] = __builtin_amdgcn_mfma_f32_16x16x32_bf16(pa, vf, o[nc], 0, 0, 0);
        }
    }

    for (int i = 0; i < 4; ++i) {
        float inv = 1.0f / lsum[i];
        int row = q0 + g * 4 + i;
        for (int nc = 0; nc < 8; ++nc) {
            O[((size_t)(b * S_ + row)) * D_ + h * HD_ + nc * 16 + lr] = f2bf(o[nc][i] * inv);
        }
    }
}

// ---------------- output GEMM: out = O @ Wout^T + b (fp32 out) ----------------
__global__ __launch_bounds__(256) void gemm_bt_out(const unsigned short* __restrict__ A,
                                                   const unsigned short* __restrict__ W,
                                                   const float* __restrict__ bias,
                                                   float* __restrict__ out) {
    __shared__ alignas(16) unsigned short As[128 * 32];
    __shared__ alignas(16) unsigned short Bs[128 * 32];
    const int t  = threadIdx.x;
    const int l  = t & 63, w = t >> 6;
    const int wr = w >> 1, wc = w & 1;
    const int lr = l & 15, g = l >> 4;
    const int m0 = blockIdx.y * 128, n0 = blockIdx.x * 128;
    const int Kd = D_;

    f32x4 zero = {0.f, 0.f, 0.f, 0.f};
    f32x4 acc[4][4];
    for (int i = 0; i < 4; ++i)
        for (int j = 0; j < 4; ++j) acc[i][j] = zero;

    const int ea = t * 8;
    const int rowA = ea >> 5, colA = ea & 31;

    for (int kt = 0; kt < Kd; kt += 32) {
        GLOAD_LDS16(A + (size_t)(m0 + rowA) * Kd + kt + colA, &As[ea]);
        GLOAD_LDS16(A + (size_t)(m0 + 64 + rowA) * Kd + kt + colA, &As[2048 + ea]);
        GLOAD_LDS16(W + (size_t)(n0 + rowA) * Kd + kt + colA, &Bs[ea]);
        GLOAD_LDS16(W + (size_t)(n0 + 64 + rowA) * Kd + kt + colA, &Bs[2048 + ea]);
        __syncthreads();
        bf16x8 af[4], bfr[4];
        for (int mi = 0; mi < 4; ++mi) af[mi]  = ld_bf8(&As[(wr * 64 + mi * 16 + lr) * 32 + g * 8]);
        for (int ni = 0; ni < 4; ++ni) bfr[ni] = ld_bf8(&Bs[(wc * 64 + ni * 16 + lr) * 32 + g * 8]);
        for (int mi = 0; mi < 4; ++mi)
            for (int ni = 0; ni < 4; ++ni)
                acc[mi][ni] = __builtin_amdgcn_mfma_f32_16x16x32_bf16(af[mi], bfr[ni], acc[mi][ni], 0, 0, 0);
        __syncthreads();
    }

    for (int mi = 0; mi < 4; ++mi) {
        for (int ni = 0; ni < 4; ++ni) {
            for (int i = 0; i < 4; ++i) {
                int m = m0 + wr * 64 + mi * 16 + g * 4 + i;
                int n = n0 + wc * 64 + ni * 16 + lr;
                out[(size_t)m * D_ + n] = acc[mi][ni][i] + bias[n];
            }
        }
    }
}

extern "C" void kernel_launch(void* const* d_in, const int* in_sizes, int n_in,
                              void* d_out, int out_size, void* d_ws, size_t ws_size,
                              hipStream_t stream) {
    (void)in_sizes; (void)n_in; (void)out_size; (void)ws_size;
    const float* x         = (const float*)d_in[0];
    const float* attn_bias = (const float*)d_in[1];
    const float* Wqkv_w    = (const float*)d_in[2];
    const float* Wqkv_b    = (const float*)d_in[3];
    const float* out_w     = (const float*)d_in[4];
    const float* out_b     = (const float*)d_in[5];
    float* out = (float*)d_out;

    char* ws = (char*)d_ws;
    unsigned short* xb    = (unsigned short*)(ws);                 // 16 MB [B*S, D] bf16
    unsigned short* wqkvb = (unsigned short*)(ws + 16777216);      // 24 MB [3D, D] bf16
    unsigned short* woutb = (unsigned short*)(ws + 41943040);      // 8 MB  [D, D] bf16
    unsigned short* Qb    = (unsigned short*)(ws + 50331648);      // 16 MB [B,H,S,hd]
    unsigned short* Kb    = (unsigned short*)(ws + 67108864);      // 16 MB
    unsigned short* Vb    = (unsigned short*)(ws + 83886080);      // 16 MB
    unsigned short* Vtb   = wqkvb;   // reuse (done after QKV GEMM)
    unsigned short* Ob    = xb;      // reuse (done after QKV GEMM)

    cast_f32_bf16<<<8192, 256, 0, stream>>>(x, xb, 8388608);
    cast_f32_bf16<<<12288, 256, 0, stream>>>(Wqkv_w, wqkvb, 12582912);
    cast_f32_bf16<<<4096, 256, 0, stream>>>(out_w, woutb, 4194304);
    gemm_bt_qkv<<<dim3(48, 32), 256, 0, stream>>>(xb, wqkvb, Wqkv_b, Qb, Kb, Vb);
    transpose_v<<<dim3(4, 64, 32), dim3(32, 8), 0, stream>>>(Vb, Vtb);
    attn_kernel<<<dim3(128, 32), 64, 0, stream>>>(Qb, Kb, Vtb, attn_bias, Ob);
    gemm_bt_out<<<dim3(16, 32), 256, 0, stream>>>(Ob, woutb, out_b, out);
}

// Round 2
// 576.871 us; speedup vs baseline: 1.3844x; 1.3844x over previous
//
#include <hip/hip_runtime.h>
#include <hip/hip_bf16.h>
#include <stdint.h>

#define H_  16
#define S_  2048
#define D_  2048
#define HD_ 128

typedef __bf16 bf16x8 __attribute__((ext_vector_type(8)));
typedef short  s16x8  __attribute__((ext_vector_type(8)));
typedef float  f32x4  __attribute__((ext_vector_type(4)));
typedef unsigned short u16x4 __attribute__((ext_vector_type(4)));

__device__ __forceinline__ unsigned short f2bf(float f) {
    unsigned u = __builtin_bit_cast(unsigned, f);
    u += 0x7fffu + ((u >> 16) & 1u);
    return (unsigned short)(u >> 16);
}

__device__ __forceinline__ bf16x8 ld_bf8(const unsigned short* p) {
    s16x8 r = *reinterpret_cast<const s16x8*>(p);
    return __builtin_bit_cast(bf16x8, r);
}

#define GLOAD_LDS16(gp, lp)                                                     \
    __builtin_amdgcn_global_load_lds(                                            \
        (const __attribute__((address_space(1))) void*)(gp),                     \
        (__attribute__((address_space(3))) void*)(lp), 16, 0, 0)

// ---------------- cast fp32 -> bf16 ----------------
__global__ __launch_bounds__(256) void cast_f32_bf16(const float* __restrict__ in,
                                                     unsigned short* __restrict__ out,
                                                     int n) {
    int i = (blockIdx.x * 256 + threadIdx.x) * 4;
    if (i >= n) return;
    float4 v = *reinterpret_cast<const float4*>(in + i);
    u16x4 o;
    o[0] = f2bf(v.x); o[1] = f2bf(v.y); o[2] = f2bf(v.z); o[3] = f2bf(v.w);
    *reinterpret_cast<u16x4*>(out + i) = o;
}

// ---------------- QKV GEMM: qkv = x @ W^T + b, scatter to Q/K/V [B,H,S,hd] ----------------
__global__ __launch_bounds__(256) void gemm_bt_qkv(const unsigned short* __restrict__ A,
                                                   const unsigned short* __restrict__ W,
                                                   const float* __restrict__ bias,
                                                   unsigned short* __restrict__ Qo,
                                                   unsigned short* __restrict__ Ko,
                                                   unsigned short* __restrict__ Vo) {
    __shared__ alignas(16) unsigned short As[128 * 32];
    __shared__ alignas(16) unsigned short Bs[128 * 32];
    const int t  = threadIdx.x;
    const int l  = t & 63, w = t >> 6;
    const int wr = w >> 1, wc = w & 1;
    const int lr = l & 15, g = l >> 4;
    const int m0 = blockIdx.y * 128, n0 = blockIdx.x * 128;
    const int Kd = D_;

    f32x4 zero = {0.f, 0.f, 0.f, 0.f};
    f32x4 acc[4][4];
    for (int i = 0; i < 4; ++i)
        for (int j = 0; j < 4; ++j) acc[i][j] = zero;

    const int ea = t * 8;
    const int rowA = ea >> 5, colA = ea & 31;

    for (int kt = 0; kt < Kd; kt += 32) {
        GLOAD_LDS16(A + (size_t)(m0 + rowA) * Kd + kt + colA, &As[ea]);
        GLOAD_LDS16(A + (size_t)(m0 + 64 + rowA) * Kd + kt + colA, &As[2048 + ea]);
        GLOAD_LDS16(W + (size_t)(n0 + rowA) * Kd + kt + colA, &Bs[ea]);
        GLOAD_LDS16(W + (size_t)(n0 + 64 + rowA) * Kd + kt + colA, &Bs[2048 + ea]);
        __syncthreads();
        bf16x8 af[4], bfr[4];
        for (int mi = 0; mi < 4; ++mi) af[mi]  = ld_bf8(&As[(wr * 64 + mi * 16 + lr) * 32 + g * 8]);
        for (int ni = 0; ni < 4; ++ni) bfr[ni] = ld_bf8(&Bs[(wc * 64 + ni * 16 + lr) * 32 + g * 8]);
        for (int mi = 0; mi < 4; ++mi)
            for (int ni = 0; ni < 4; ++ni)
                acc[mi][ni] = __builtin_amdgcn_mfma_f32_16x16x32_bf16(af[mi], bfr[ni], acc[mi][ni], 0, 0, 0);
        __syncthreads();
    }

    for (int mi = 0; mi < 4; ++mi) {
        for (int ni = 0; ni < 4; ++ni) {
            for (int i = 0; i < 4; ++i) {
                int m = m0 + wr * 64 + mi * 16 + g * 4 + i;
                int n = n0 + wc * 64 + ni * 16 + lr;
                float v = acc[mi][ni][i] + bias[n];
                int which = n >> 11;
                int n2 = n & 2047;
                int h = n2 >> 7, d = n2 & 127;
                int b = m >> 11, s = m & 2047;
                size_t idx = (((size_t)(b * H_ + h)) * S_ + s) * HD_ + d;
                unsigned short bv = f2bf(v);
                if (which == 0)      Qo[idx] = bv;
                else if (which == 1) Ko[idx] = bv;
                else                 Vo[idx] = bv;
            }
        }
    }
}

// ---------------- transpose V [B,H,S,hd] -> Vt [B,H,hd,S] ----------------
__global__ void transpose_v(const unsigned short* __restrict__ V,
                            unsigned short* __restrict__ Vt) {
    __shared__ alignas(16) unsigned short tile[32][33];
    const int bh = blockIdx.z;
    const int d0 = blockIdx.x * 32, s0 = blockIdx.y * 32;
    const int tx = threadIdx.x, ty = threadIdx.y;
    for (int r = 0; r < 4; ++r) {
        int s = s0 + ty + r * 8;
        tile[ty + r * 8][tx] = V[((size_t)bh * S_ + s) * HD_ + d0 + tx];
    }
    __syncthreads();
    for (int r = 0; r < 4; ++r) {
        int d = d0 + ty + r * 8;
        Vt[((size_t)bh * HD_ + d) * S_ + s0 + tx] = tile[tx][ty + r * 8];
    }
}

// ---------------- fused attention: 4 waves/block, 64 q-rows, 64-key chunks ----------------
__global__ __launch_bounds__(256) void attn_kernel(const unsigned short* __restrict__ Q,
                                                   const unsigned short* __restrict__ K,
                                                   const unsigned short* __restrict__ Vt,
                                                   const float* __restrict__ bias,
                                                   unsigned short* __restrict__ O) {
    __shared__ alignas(16) float biasLds[2][64 * 64];         // 32 KB double-buffered
    __shared__ alignas(16) unsigned short Pbuf[4][16 * 64];   // 8 KB, per-wave, XOR-swizzled

    const int t  = threadIdx.x;
    const int l  = t & 63, w = t >> 6;
    const int lr = l & 15, g = l >> 4;

    // bijective XCD-chunked swizzle over 1024 blocks; heavy q-tiles first within each head
    const int raw = blockIdx.x;
    const int swz = (raw & 7) * 128 + (raw >> 3);
    const int bh  = swz >> 5;
    const int qt  = 31 - (swz & 31);
    const int h   = bh & (H_ - 1), b = bh >> 4;

    const unsigned short* Qb = Q + (size_t)bh * S_ * HD_;
    const unsigned short* Kb = K + (size_t)bh * S_ * HD_;
    const unsigned short* Vb = Vt + (size_t)bh * HD_ * S_;
    const float* Bb = bias + (size_t)h * S_ * S_;
    const float scale = 0.08838834764831845f;  // 1/sqrt(128)

    const int q0b = qt * 64;          // block's first q row
    const int q0  = q0b + w * 16;     // this wave's first q row

    bf16x8 qf[4];
    for (int dc = 0; dc < 4; ++dc)
        qf[dc] = ld_bf8(Qb + (size_t)(q0 + lr) * HD_ + dc * 32 + g * 8);

    f32x4 zero = {0.f, 0.f, 0.f, 0.f};
    f32x4 o[8];
    for (int nc = 0; nc < 8; ++nc) o[nc] = zero;
    float mrow[4], lsum[4];
    for (int i = 0; i < 4; ++i) { mrow[i] = -3.0e38f; lsum[i] = 0.f; }

    // stage bias tile for chunk 0: rows q0b..q0b+63, cols 0..63, each wave stages its 16 rows
    {
        const int rbase = w * 16;
#pragma unroll
        for (int j = 0; j < 4; ++j) {
            int r0 = rbase + j * 4;
            GLOAD_LDS16(Bb + (size_t)(q0b + r0 + (l >> 4)) * S_ + (l & 15) * 4,
                        &biasLds[0][r0 * 64 + l * 4]);
        }
    }
    __syncthreads();

    for (int c = 0; c <= qt; ++c) {
        const int k0 = c << 6;
        const float* bl = biasLds[c & 1];

        // async prefetch next bias tile while computing this chunk
        if (c < qt) {
            float* bl2 = biasLds[(c & 1) ^ 1];
            const int k1 = k0 + 64;
            const int rbase = w * 16;
#pragma unroll
            for (int j = 0; j < 4; ++j) {
                int r0 = rbase + j * 4;
                GLOAD_LDS16(Bb + (size_t)(q0b + r0 + (l >> 4)) * S_ + k1 + (l & 15) * 4,
                            &biasLds[((c & 1) ^ 1)][r0 * 64 + l * 4]);
            }
            (void)bl2;
        }

        // QK^T: 16 q-rows x 64 keys
        f32x4 s[4];
        for (int kc = 0; kc < 4; ++kc) s[kc] = zero;
#pragma unroll
        for (int kc = 0; kc < 4; ++kc) {
#pragma unroll
            for (int dc = 0; dc < 4; ++dc) {
                bf16x8 kf = ld_bf8(Kb + (size_t)(k0 + kc * 16 + lr) * HD_ + dc * 32 + g * 8);
                s[kc] = __builtin_amdgcn_mfma_f32_16x16x32_bf16(qf[dc], kf, s[kc], 0, 0, 0);
            }
        }

        const bool last = (c == qt);
        float corr[4];
        unsigned short* Pw = Pbuf[w];
#pragma unroll
        for (int i = 0; i < 4; ++i) {
            const int rowl = w * 16 + g * 4 + i;   // row within block tile (bias LDS row)
            const int prow = g * 4 + i;            // row within wave (Pbuf row)
            float v[4];
#pragma unroll
            for (int kc = 0; kc < 4; ++kc) {
                v[kc] = s[kc][i] * scale + bl[rowl * 64 + kc * 16 + lr];
            }
            if (last) {
                const int grow_rel = rowl;         // key offset within chunk vs row
#pragma unroll
                for (int kc = 0; kc < 4; ++kc)
                    if (kc * 16 + lr > grow_rel) v[kc] = -3.0e38f;
            }
            float mx = fmaxf(fmaxf(v[0], v[1]), fmaxf(v[2], v[3]));
            mx = fmaxf(mx, __shfl_xor(mx, 1));
            mx = fmaxf(mx, __shfl_xor(mx, 2));
            mx = fmaxf(mx, __shfl_xor(mx, 4));
            mx = fmaxf(mx, __shfl_xor(mx, 8));
            float mnew = fmaxf(mrow[i], mx);
            float cf = __expf(mrow[i] - mnew);
            mrow[i] = mnew;
            float e0 = __expf(v[0] - mnew);
            float e1 = __expf(v[1] - mnew);
            float e2 = __expf(v[2] - mnew);
            float e3 = __expf(v[3] - mnew);
            float rs = (e0 + e1) + (e2 + e3);
            rs += __shfl_xor(rs, 1);
            rs += __shfl_xor(rs, 2);
            rs += __shfl_xor(rs, 4);
            rs += __shfl_xor(rs, 8);
            lsum[i] = lsum[i] * cf + rs;
            corr[i] = cf;
            const int sw = (prow & 7) << 3;
            Pw[(prow * 64 + 0  + lr) ^ sw] = f2bf(e0);
            Pw[(prow * 64 + 16 + lr) ^ sw] = f2bf(e1);
            Pw[(prow * 64 + 32 + lr) ^ sw] = f2bf(e2);
            Pw[(prow * 64 + 48 + lr) ^ sw] = f2bf(e3);
        }
#pragma unroll
        for (int nc = 0; nc < 8; ++nc)
#pragma unroll
            for (int i = 0; i < 4; ++i) o[nc][i] *= corr[i];

        // PV: P[16x64] @ V^T-chunk -> o[8] (cols = head dims)
#pragma unroll
        for (int kc2 = 0; kc2 < 2; ++kc2) {
            bf16x8 pa = ld_bf8(&Pw[(lr * 64 + kc2 * 32 + g * 8) ^ ((lr & 7) << 3)]);
#pragma unroll
            for (int nc = 0; nc < 8; ++nc) {
                bf16x8 vf = ld_bf8(Vb + (size_t)(nc * 16 + lr) * S_ + k0 + kc2 * 32 + g * 8);
                o[nc] = __builtin_amdgcn_mfma_f32_16x16x32_bf16(pa, vf, o[nc], 0, 0, 0);
            }
        }

        __syncthreads();   // drains vmcnt (prefetch complete) + publishes next bias tile
    }

    for (int i = 0; i < 4; ++i) {
        float inv = 1.0f / lsum[i];
        int row = q0 + g * 4 + i;
        for (int nc = 0; nc < 8; ++nc) {
            O[((size_t)(b * S_ + row)) * D_ + h * HD_ + nc * 16 + lr] = f2bf(o[nc][i] * inv);
        }
    }
}

// ---------------- output GEMM: out = O @ Wout^T + b (fp32 out) ----------------
__global__ __launch_bounds__(256) void gemm_bt_out(const unsigned short* __restrict__ A,
                                                   const unsigned short* __restrict__ W,
                                                   const float* __restrict__ bias,
                                                   float* __restrict__ out) {
    __shared__ alignas(16) unsigned short As[128 * 32];
    __shared__ alignas(16) unsigned short Bs[128 * 32];
    const int t  = threadIdx.x;
    const int l  = t & 63, w = t >> 6;
    const int wr = w >> 1, wc = w & 1;
    const int lr = l & 15, g = l >> 4;
    const int m0 = blockIdx.y * 128, n0 = blockIdx.x * 128;
    const int Kd = D_;

    f32x4 zero = {0.f, 0.f, 0.f, 0.f};
    f32x4 acc[4][4];
    for (int i = 0; i < 4; ++i)
        for (int j = 0; j < 4; ++j) acc[i][j] = zero;

    const int ea = t * 8;
    const int rowA = ea >> 5, colA = ea & 31;

    for (int kt = 0; kt < Kd; kt += 32) {
        GLOAD_LDS16(A + (size_t)(m0 + rowA) * Kd + kt + colA, &As[ea]);
        GLOAD_LDS16(A + (size_t)(m0 + 64 + rowA) * Kd + kt + colA, &As[2048 + ea]);
        GLOAD_LDS16(W + (size_t)(n0 + rowA) * Kd + kt + colA, &Bs[ea]);
        GLOAD_LDS16(W + (size_t)(n0 + 64 + rowA) * Kd + kt + colA, &Bs[2048 + ea]);
        __syncthreads();
        bf16x8 af[4], bfr[4];
        for (int mi = 0; mi < 4; ++mi) af[mi]  = ld_bf8(&As[(wr * 64 + mi * 16 + lr) * 32 + g * 8]);
        for (int ni = 0; ni < 4; ++ni) bfr[ni] = ld_bf8(&Bs[(wc * 64 + ni * 16 + lr) * 32 + g * 8]);
        for (int mi = 0; mi < 4; ++mi)
            for (int ni = 0; ni < 4; ++ni)
                acc[mi][ni] = __builtin_amdgcn_mfma_f32_16x16x32_bf16(af[mi], bfr[ni], acc[mi][ni], 0, 0, 0);
        __syncthreads();
    }

    for (int mi = 0; mi < 4; ++mi) {
        for (int ni = 0; ni < 4; ++ni) {
            for (int i = 0; i < 4; ++i) {
                int m = m0 + wr * 64 + mi * 16 + g * 4 + i;
                int n = n0 + wc * 64 + ni * 16 + lr;
                out[(size_t)m * D_ + n] = acc[mi][ni][i] + bias[n];
            }
        }
    }
}

extern "C" void kernel_launch(void* const* d_in, const int* in_sizes, int n_in,
                              void* d_out, int out_size, void* d_ws, size_t ws_size,
                              hipStream_t stream) {
    (void)in_sizes; (void)n_in; (void)out_size; (void)ws_size;
    const float* x         = (const float*)d_in[0];
    const float* attn_bias = (const float*)d_in[1];
    const float* Wqkv_w    = (const float*)d_in[2];
    const float* Wqkv_b    = (const float*)d_in[3];
    const float* out_w     = (const float*)d_in[4];
    const float* out_b     = (const float*)d_in[5];
    float* out = (float*)d_out;

    char* ws = (char*)d_ws;
    unsigned short* xb    = (unsigned short*)(ws);                 // 16 MB [B*S, D] bf16
    unsigned short* wqkvb = (unsigned short*)(ws + 16777216);      // 24 MB [3D, D] bf16
    unsigned short* woutb = (unsigned short*)(ws + 41943040);      // 8 MB  [D, D] bf16
    unsigned short* Qb    = (unsigned short*)(ws + 50331648);      // 16 MB [B,H,S,hd]
    unsigned short* Kb    = (unsigned short*)(ws + 67108864);      // 16 MB
    unsigned short* Vb    = (unsigned short*)(ws + 83886080);      // 16 MB
    unsigned short* Vtb   = wqkvb;   // reuse (done after QKV GEMM)
    unsigned short* Ob    = xb;      // reuse (done after QKV GEMM)

    cast_f32_bf16<<<8192, 256, 0, stream>>>(x, xb, 8388608);
    cast_f32_bf16<<<12288, 256, 0, stream>>>(Wqkv_w, wqkvb, 12582912);
    cast_f32_bf16<<<4096, 256, 0, stream>>>(out_w, woutb, 4194304);
    gemm_bt_qkv<<<dim3(48, 32), 256, 0, stream>>>(xb, wqkvb, Wqkv_b, Qb, Kb, Vb);
    transpose_v<<<dim3(4, 64, 32), dim3(32, 8), 0, stream>>>(Vb, Vtb);
    attn_kernel<<<1024, 256, 0, stream>>>(Qb, Kb, Vtb, attn_bias, Ob);
    gemm_bt_out<<<dim3(16, 32), 256, 0, stream>>>(Ob, woutb, out_b, out);
}